// Round 1
// baseline (402.494 us; speedup 1.0000x reference)
//
#include <hip/hip_runtime.h>

// SConv2dAvg: out[b,o,y,x] = sum_{c,kh,kw} in[b,c,2y+selh[y,x]+kh, 2x+selw[y,x]+kw] * W[o,c,kh,kw] + bias[o]
// B=16 Cin=64 H=W=128 Cout=64 oh=ow=63 stride=2, all fp32.

#define B_    16
#define CIN   64
#define H_    128
#define W_    128
#define COUT  64
#define OH    63
#define OW    63
#define NPIX  (OH * OW)      // 3969
#define KTOT  (CIN * 9)      // 576
#define PPB   4              // pixels per block
#define MB    (PPB * B_)     // 64 rows (pixel-local, batch)
#define KC    72             // k-chunk = 8 channels * 9 taps
#define NCH   8              // 576 / 72
#define LDA   76             // padded LDS stride (76*4B: 16B aligned, <=2-way bank alias)
#define LDW   76

__global__ __launch_bounds__(256, 4)
void sconv2davg_kernel(const float* __restrict__ in,
                       const float* __restrict__ wgt,
                       const float* __restrict__ bias,
                       const int* __restrict__ selh,
                       const int* __restrict__ selw,
                       float* __restrict__ out) {
    __shared__ float As[MB * LDA];     // A[m][k_local], m = pix_local*16 + b
    __shared__ float Ws[COUT * LDW];   // W[o][k_local]
    __shared__ int hb_s[PPB], wb_s[PPB];

    const int tid = threadIdx.x;
    const int p0  = blockIdx.x * PPB;

    if (tid < PPB) {
        int p = p0 + tid;
        if (p > NPIX - 1) p = NPIX - 1;   // tail clamp (loads valid, stores guarded)
        int y = p / OW;
        int x = p - y * OW;
        hb_s[tid] = 2 * y + selh[p];
        wb_s[tid] = 2 * x + selw[p];
    }
    __syncthreads();

    const int tn = tid & 15;    // n-group: this thread's Cout = tn + 16*j
    const int tm = tid >> 4;    // m-group: rows 4*tm .. 4*tm+3

    float acc[4][4];
#pragma unroll
    for (int i = 0; i < 4; ++i)
#pragma unroll
        for (int j = 0; j < 4; ++j) acc[i][j] = 0.0f;

    for (int cc = 0; cc < NCH; ++cc) {
        const int c0 = cc * 8;          // first input channel of this chunk

        // ---- gather A chunk: 64 m * 72 k = 4608 elements, 18 per thread ----
#pragma unroll
        for (int it = 0; it < 18; ++it) {
            int idx = tid + it * 256;
            int m   = idx / KC;             // 0..63
            int rem = idx - m * KC;         // k_local 0..71
            int cl  = rem / 9;
            int r   = rem - cl * 9;
            int kh  = r / 3;
            int kw  = r - kh * 3;
            int pl  = m >> 4;
            int b   = m & 15;
            int ih  = hb_s[pl] + kh;
            int iw  = wb_s[pl] + kw;
            As[m * LDA + rem] =
                in[(((b * CIN) + (c0 + cl)) * H_ + ih) * W_ + iw];
        }

        // ---- load W chunk: 64 o * 72 k, coalesced (k contiguous in global) ----
#pragma unroll
        for (int it = 0; it < 18; ++it) {
            int idx = tid + it * 256;
            int o   = idx / KC;
            int kk  = idx - o * KC;
            Ws[o * LDW + kk] = wgt[o * KTOT + cc * KC + kk];
        }
        __syncthreads();

        // ---- compute: 18 k-groups of 4; 8 x b128 LDS reads per 64 FMA ----
#pragma unroll 2
        for (int k0 = 0; k0 < KC; k0 += 4) {
            float4 a[4], w[4];
#pragma unroll
            for (int i = 0; i < 4; ++i)
                a[i] = *(const float4*)&As[(4 * tm + i) * LDA + k0];
#pragma unroll
            for (int j = 0; j < 4; ++j)
                w[j] = *(const float4*)&Ws[(tn + 16 * j) * LDW + k0];
#pragma unroll
            for (int i = 0; i < 4; ++i)
#pragma unroll
                for (int j = 0; j < 4; ++j) {
                    acc[i][j] += a[i].x * w[j].x;
                    acc[i][j] += a[i].y * w[j].y;
                    acc[i][j] += a[i].z * w[j].z;
                    acc[i][j] += a[i].w * w[j].w;
                }
        }
        __syncthreads();
    }

    // ---- epilogue: thread's 4 m are 4 consecutive b of ONE pixel ----
    const int pl = tm >> 2;                 // pixel-local index (const per thread)
    const int p  = p0 + pl;
    float bs[4];
#pragma unroll
    for (int j = 0; j < 4; ++j) bs[j] = bias[tn + 16 * j];

    if (p < NPIX) {
#pragma unroll
        for (int i = 0; i < 4; ++i) {
            int b = ((tm & 3) * 4 + i);     // batch index
#pragma unroll
            for (int j = 0; j < 4; ++j) {
                int o = tn + 16 * j;
                out[((b * COUT) + o) * NPIX + p] = acc[i][j] + bs[j];
            }
        }
    }
}

extern "C" void kernel_launch(void* const* d_in, const int* in_sizes, int n_in,
                              void* d_out, int out_size, void* d_ws, size_t ws_size,
                              hipStream_t stream) {
    const float* in   = (const float*)d_in[0];
    const float* wgt  = (const float*)d_in[1];
    const float* bias = (const float*)d_in[2];
    const int*   selh = (const int*)d_in[3];
    const int*   selw = (const int*)d_in[4];
    float* out = (float*)d_out;

    const int nblocks = (NPIX + PPB - 1) / PPB;   // 993
    sconv2davg_kernel<<<nblocks, 256, 0, stream>>>(in, wgt, bias, selh, selw, out);
}

// Round 2
// 204.810 us; speedup vs baseline: 1.9652x; 1.9652x over previous
//
#include <hip/hip_runtime.h>

// SConv2dAvg: out[b,o,y,x] = sum_{c,kh,kw} in[b,c,2y+selh+kh,2x+selw+kw] * W[o,c,kh,kw] + bias[o]
// B=16 Cin=64 H=W=128 Cout=64 oh=ow=63 stride=2, fp32.
// Strategy: NCHW->NHWC repack in d_ws (stage 1), then implicit-GEMM with
// channel-contiguous 64B gathers and 16-pixel output runs (stage 2).

#define B_    16
#define CIN   64
#define H_    128
#define W_    128
#define COUT  64
#define OH    63
#define OW    63
#define NPIX  (OH * OW)      // 3969
#define KTOT  (CIN * 9)      // 576

// ---------------- stage 1a: input NCHW -> NHWC ----------------
__global__ __launch_bounds__(256)
void transpose_nhwc_kernel(const float* __restrict__ in, float* __restrict__ nhwc) {
    __shared__ float T[64 * 65];            // T[c][w], pad 65
    const int tid = threadIdx.x;
    const int w0  = blockIdx.x * 64;
    const int h   = blockIdx.y;
    const int b   = blockIdx.z;

    // load: 64 c x 64 w, coalesced along w
    {
        const int w4 = tid & 15;            // float4 index along w
        const int cl = tid >> 4;            // 0..15
#pragma unroll
        for (int i = 0; i < 4; ++i) {
            const int c = cl + 16 * i;
            const float4 v = *(const float4*)&in[((b * CIN + c) * H_ + h) * W_ + w0 + 4 * w4];
            T[c * 65 + 4 * w4 + 0] = v.x;
            T[c * 65 + 4 * w4 + 1] = v.y;
            T[c * 65 + 4 * w4 + 2] = v.z;
            T[c * 65 + 4 * w4 + 3] = v.w;
        }
    }
    __syncthreads();
    // store: coalesced along c
    {
        const int cq = tid & 15;            // c = 4*cq .. 4*cq+3
        const int wl = tid >> 4;            // 0..15
#pragma unroll
        for (int i = 0; i < 4; ++i) {
            const int w = wl + 16 * i;
            float4 v;
            v.x = T[(4 * cq + 0) * 65 + w];
            v.y = T[(4 * cq + 1) * 65 + w];
            v.z = T[(4 * cq + 2) * 65 + w];
            v.w = T[(4 * cq + 3) * 65 + w];
            *(float4*)&nhwc[((b * H_ + h) * W_ + w0 + w) * CIN + 4 * cq] = v;
        }
    }
}

// ---------------- stage 1b: weight (o,c,tap) -> (o,tap,c) ----------------
__global__ __launch_bounds__(576)
void transpose_wgt_kernel(const float* __restrict__ wgt, float* __restrict__ wgt_t) {
    const int o = blockIdx.x;
    const int t = threadIdx.x;              // 0..575
    const int c = t / 9;
    const int tap = t - c * 9;
    wgt_t[o * KTOT + tap * CIN + c] = wgt[o * KTOT + c * 9 + tap];
}

// ---------------- stage 2: implicit GEMM ----------------
// block tile: 16 pixels x 4 batches (M=64) x 64 Cout.  K chunked 16c*9tap=144.
#define PIXT  16
#define BT    4
#define KC    144
#define NCH   4
#define LDA   148   // pad: rows 16B-aligned (148*4=592=37*16)
#define LDO   68    // epilogue staging stride

__global__ __launch_bounds__(256, 2)
void sconv2davg_gemm(const float* __restrict__ nhwc,
                     const float* __restrict__ wgt_t,
                     const float* __restrict__ bias,
                     const int* __restrict__ selh,
                     const int* __restrict__ selw,
                     float* __restrict__ out) {
    __shared__ float As[64 * LDA];
    __shared__ float Ws[64 * LDA];
    __shared__ int hb_s[PIXT], wb_s[PIXT];

    const int tid = threadIdx.x;
    const int p0  = blockIdx.x * PIXT;
    const int b0  = blockIdx.y * BT;

    if (tid < PIXT) {
        int p = p0 + tid;
        if (p > NPIX - 1) p = NPIX - 1;     // clamp; stores guarded later
        int y = p / OW;
        int x = p - y * OW;
        hb_s[tid] = 2 * y + selh[p];
        wb_s[tid] = 2 * x + selw[p];
    }
    __syncthreads();

    const int tn = tid & 15;                // Cout = tn + 16*j
    const int tm = tid >> 4;                // rows 4*tm .. 4*tm+3

    float acc[4][4];
#pragma unroll
    for (int i = 0; i < 4; ++i)
#pragma unroll
        for (int j = 0; j < 4; ++j) acc[i][j] = 0.0f;

    // gather/load thread mapping: m|o = tid/4, q = tid%4 (float4 within 16 c)
    const int gm = tid >> 2;
    const int gq = tid & 3;
    const int pl = gm >> 2;                 // pixel-local (m = pl*4 + bl)
    const int bl = gm & 3;
    const int gb = b0 + bl;
    const int ih0 = hb_s[pl];
    const int iw0 = wb_s[pl];

    for (int cc = 0; cc < NCH; ++cc) {
        const int c0 = cc * 16;

        // A-tile: per (m, tap): 16 contiguous channels = 4 x float4 (64B segs)
#pragma unroll
        for (int tap = 0; tap < 9; ++tap) {
            const int kh = tap / 3, kw = tap - 3 * (tap / 3);
            const float4 v = *(const float4*)
                &nhwc[((gb * H_ + ih0 + kh) * W_ + iw0 + kw) * CIN + c0 + 4 * gq];
            *(float4*)&As[gm * LDA + tap * 16 + 4 * gq] = v;
        }
        // W-tile: coalesced from (o, tap, c)
#pragma unroll
        for (int tap = 0; tap < 9; ++tap) {
            const float4 v = *(const float4*)
                &wgt_t[gm * KTOT + tap * CIN + c0 + 4 * gq];
            *(float4*)&Ws[gm * LDA + tap * 16 + 4 * gq] = v;
        }
        __syncthreads();

#pragma unroll 2
        for (int k0 = 0; k0 < KC; k0 += 4) {
            float4 a[4], w[4];
#pragma unroll
            for (int i = 0; i < 4; ++i)
                a[i] = *(const float4*)&As[(4 * tm + i) * LDA + k0];
#pragma unroll
            for (int j = 0; j < 4; ++j)
                w[j] = *(const float4*)&Ws[(tn + 16 * j) * LDA + k0];
#pragma unroll
            for (int i = 0; i < 4; ++i)
#pragma unroll
                for (int j = 0; j < 4; ++j) {
                    acc[i][j] += a[i].x * w[j].x;
                    acc[i][j] += a[i].y * w[j].y;
                    acc[i][j] += a[i].z * w[j].z;
                    acc[i][j] += a[i].w * w[j].w;
                }
        }
        __syncthreads();
    }

    // epilogue: transpose through LDS so each (b,o) row writes 16 consecutive p
    float* Ot = As;                         // reuse (post-barrier)
    float bs[4];
#pragma unroll
    for (int j = 0; j < 4; ++j) bs[j] = bias[tn + 16 * j];
#pragma unroll
    for (int i = 0; i < 4; ++i) {
        const int m = 4 * tm + i;
#pragma unroll
        for (int j = 0; j < 4; ++j)
            Ot[m * LDO + tn + 16 * j] = acc[i][j] + bs[j];
    }
    __syncthreads();

    {
        const int o  = tid & 63;
        const int b2 = tid >> 6;            // 0..3
        const int rowbase = ((b0 + b2) * COUT + o) * NPIX;
#pragma unroll
        for (int pp = 0; pp < PIXT; ++pp) {
            const int p = p0 + pp;
            if (p < NPIX)
                out[rowbase + p] = Ot[(pp * 4 + b2) * LDO + o];
        }
    }
}

// ---------------- fallback (round-1 kernel) if ws too small ----------------
#define FKC   72
#define FLDA  76
__global__ __launch_bounds__(256, 4)
void sconv2davg_fallback(const float* __restrict__ in,
                         const float* __restrict__ wgt,
                         const float* __restrict__ bias,
                         const int* __restrict__ selh,
                         const int* __restrict__ selw,
                         float* __restrict__ out) {
    __shared__ float As[64 * FLDA];
    __shared__ float Ws[64 * FLDA];
    __shared__ int hb_s[4], wb_s[4];
    const int tid = threadIdx.x;
    const int p0  = blockIdx.x * 4;
    if (tid < 4) {
        int p = p0 + tid;
        if (p > NPIX - 1) p = NPIX - 1;
        int y = p / OW;
        int x = p - y * OW;
        hb_s[tid] = 2 * y + selh[p];
        wb_s[tid] = 2 * x + selw[p];
    }
    __syncthreads();
    const int tn = tid & 15, tm = tid >> 4;
    float acc[4][4];
#pragma unroll
    for (int i = 0; i < 4; ++i)
#pragma unroll
        for (int j = 0; j < 4; ++j) acc[i][j] = 0.0f;
    for (int cc = 0; cc < 8; ++cc) {
        const int c0 = cc * 8;
#pragma unroll
        for (int it = 0; it < 18; ++it) {
            int idx = tid + it * 256;
            int m = idx / FKC, rem = idx - m * FKC;
            int cl = rem / 9, r = rem - cl * 9;
            int kh = r / 3, kw = r - kh * 3;
            As[m * FLDA + rem] =
                in[((((m & 15) * CIN) + (c0 + cl)) * H_ + hb_s[m >> 4] + kh) * W_ + wb_s[m >> 4] + kw];
        }
#pragma unroll
        for (int it = 0; it < 18; ++it) {
            int idx = tid + it * 256;
            int o = idx / FKC, kk = idx - o * FKC;
            Ws[o * FLDA + kk] = wgt[o * KTOT + cc * FKC + kk];
        }
        __syncthreads();
#pragma unroll 2
        for (int k0 = 0; k0 < FKC; k0 += 4) {
            float4 a[4], w[4];
#pragma unroll
            for (int i = 0; i < 4; ++i) a[i] = *(const float4*)&As[(4 * tm + i) * FLDA + k0];
#pragma unroll
            for (int j = 0; j < 4; ++j) w[j] = *(const float4*)&Ws[(tn + 16 * j) * FLDA + k0];
#pragma unroll
            for (int i = 0; i < 4; ++i)
#pragma unroll
                for (int j = 0; j < 4; ++j) {
                    acc[i][j] += a[i].x * w[j].x; acc[i][j] += a[i].y * w[j].y;
                    acc[i][j] += a[i].z * w[j].z; acc[i][j] += a[i].w * w[j].w;
                }
        }
        __syncthreads();
    }
    const int p = p0 + (tm >> 2);
    if (p < NPIX) {
#pragma unroll
        for (int i = 0; i < 4; ++i) {
            int b = (tm & 3) * 4 + i;
#pragma unroll
            for (int j = 0; j < 4; ++j)
                out[((b * COUT) + tn + 16 * j) * NPIX + p] = acc[i][j] + bias[tn + 16 * j];
        }
    }
}

extern "C" void kernel_launch(void* const* d_in, const int* in_sizes, int n_in,
                              void* d_out, int out_size, void* d_ws, size_t ws_size,
                              hipStream_t stream) {
    const float* in   = (const float*)d_in[0];
    const float* wgt  = (const float*)d_in[1];
    const float* bias = (const float*)d_in[2];
    const int*   selh = (const int*)d_in[3];
    const int*   selw = (const int*)d_in[4];
    float* out = (float*)d_out;

    const size_t nhwc_elems = (size_t)B_ * H_ * W_ * CIN;        // 16.7M
    const size_t need = (nhwc_elems + (size_t)COUT * KTOT) * 4;  // ~67.3 MB

    if (ws_size >= need) {
        float* nhwc  = (float*)d_ws;
        float* wgt_t = nhwc + nhwc_elems;
        transpose_nhwc_kernel<<<dim3(W_ / 64, H_, B_), 256, 0, stream>>>(in, nhwc);
        transpose_wgt_kernel<<<COUT, 576, 0, stream>>>(wgt, wgt_t);
        const int ptiles = (NPIX + PIXT - 1) / PIXT;             // 249
        sconv2davg_gemm<<<dim3(ptiles, B_ / BT), 256, 0, stream>>>(
            nhwc, wgt_t, bias, selh, selw, out);
    } else {
        sconv2davg_fallback<<<(NPIX + 3) / 4, 256, 0, stream>>>(
            in, wgt, bias, selh, selw, out);
    }
}

// Round 3
// 141.678 us; speedup vs baseline: 2.8409x; 1.4456x over previous
//
#include <hip/hip_runtime.h>

// SConv2dAvg: out[b,o,y,x] = sum_{c,kh,kw} in[b,c,2y+selh+kh,2x+selw+kw] * W[o,c,kh,kw] + bias[o]
// B=16 Cin=64 H=W=128 Cout=64 oh=ow=63 stride=2, fp32 in/out.
// Round 3: NCHW->NHWC repack WITH fp32->bf16 cast (stage 1), then implicit GEMM
// on matrix cores (mfma_f32_16x16x32_bf16), fp32 accumulate.
// LDS tile layout [tap][row][32ch]: one MFMA K-step == one tap; every
// ds_read_b128/ds_write_b128 is exactly 8 words/bank (zero conflicts).

#define B_    16
#define CIN   64
#define H_    128
#define W_    128
#define COUT  64
#define OH    63
#define OW    63
#define NPIX  (OH * OW)      // 3969
#define KTOT  (CIN * 9)      // 576

typedef short  short8  __attribute__((ext_vector_type(8)));
typedef float  float4v __attribute__((ext_vector_type(4)));

__device__ inline short f2bf(float f) {     // RN-to-even fp32 -> bf16 bits
    union { float f; unsigned u; } x; x.f = f;
    unsigned r = x.u + 0x7fffu + ((x.u >> 16) & 1u);
    return (short)(r >> 16);
}

// ---------------- stage 1a: input NCHW fp32 -> NHWC bf16 ----------------
__global__ __launch_bounds__(256)
void transpose_nhwc_bf16(const float* __restrict__ in, short* __restrict__ nhwc) {
    __shared__ float T[64 * 65];            // T[c][w], pad 65
    const int tid = threadIdx.x;
    const int w0  = blockIdx.x * 64;
    const int h   = blockIdx.y;
    const int b   = blockIdx.z;

    {   // load 64c x 64w, coalesced along w
        const int w4 = tid & 15;
        const int cl = tid >> 4;
#pragma unroll
        for (int i = 0; i < 4; ++i) {
            const int c = cl + 16 * i;
            const float4 v = *(const float4*)&in[((b * CIN + c) * H_ + h) * W_ + w0 + 4 * w4];
            T[c * 65 + 4 * w4 + 0] = v.x;
            T[c * 65 + 4 * w4 + 1] = v.y;
            T[c * 65 + 4 * w4 + 2] = v.z;
            T[c * 65 + 4 * w4 + 3] = v.w;
        }
    }
    __syncthreads();
    {   // store: 8 channels/thread as one 16B bf16 vector, coalesced along c
        const int cg = tid & 7;             // channel group (8 ch)
        const int wl = tid >> 3;            // 0..31
#pragma unroll
        for (int i = 0; i < 2; ++i) {
            const int w = wl + 32 * i;
            short8 v;
#pragma unroll
            for (int t = 0; t < 8; ++t)
                v[t] = f2bf(T[(8 * cg + t) * 65 + w]);
            *(short8*)&nhwc[((b * H_ + h) * W_ + w0 + w) * CIN + 8 * cg] = v;
        }
    }
}

// ---------------- stage 1b: weight (o,c,tap) fp32 -> (o,tap,c) bf16 ----------------
__global__ __launch_bounds__(576)
void transpose_wgt_bf16(const float* __restrict__ wgt, short* __restrict__ wgt_t) {
    const int o = blockIdx.x;
    const int t = threadIdx.x;              // 0..575
    const int c = t / 9;
    const int tap = t - c * 9;
    wgt_t[o * KTOT + tap * CIN + c] = f2bf(wgt[o * KTOT + c * 9 + tap]);
}

// ---------------- stage 2: MFMA implicit GEMM ----------------
// block: 16 pixels x 4 batches (M=64) x 64 Cout.  2 chunks of 32 channels;
// per chunk K = 9 taps x 32 = 288, MFMA K-step = one tap.
#define PIXT  16
#define BT    4
#define LDO   68    // epilogue staging stride (floats)

__global__ __launch_bounds__(256, 2)
void sconv2davg_mfma(const short* __restrict__ nhwc,
                     const short* __restrict__ wgt_t,
                     const float* __restrict__ bias,
                     const int* __restrict__ selh,
                     const int* __restrict__ selw,
                     float* __restrict__ out) {
    __shared__ __align__(16) short As[9 * 64 * 32];   // [tap][m][cl]  36.9 KB
    __shared__ __align__(16) short Ws[9 * 64 * 32];   // [tap][o][cl]  36.9 KB
    __shared__ int hb_s[PIXT], wb_s[PIXT];

    const int tid = threadIdx.x;
    const int p0  = blockIdx.x * PIXT;
    const int b0  = blockIdx.y * BT;

    if (tid < PIXT) {
        int p = p0 + tid;
        if (p > NPIX - 1) p = NPIX - 1;     // tail clamp; stores guarded
        int y = p / OW;
        int x = p - y * OW;
        hb_s[tid] = 2 * y + selh[p];
        wb_s[tid] = 2 * x + selw[p];
    }
    __syncthreads();

    // MFMA lane decomposition
    const int ln = tid & 15;                // col within 16
    const int hl = (tid >> 4) & 3;          // k-half quad
    const int wv = tid >> 6;                // wave id: M-strip rows 16*wv..+15

    // gather mapping: row gm = pl*4+bl, seg = 16B (8ch) segment
    const int gm  = tid >> 2;
    const int seg = tid & 3;
    const int pl  = gm >> 2;
    const int bl  = gm & 3;
    const int gb  = b0 + bl;
    const int ih0 = hb_s[pl];
    const int iw0 = wb_s[pl];

    float4v acc[4];
#pragma unroll
    for (int j = 0; j < 4; ++j) acc[j] = (float4v){0.f, 0.f, 0.f, 0.f};

    for (int cc = 0; cc < 2; ++cc) {
        const int c0 = cc * 32;

        // A-gather: per (m, tap) 32 contiguous bf16 channels; 16B per thread
#pragma unroll
        for (int tap = 0; tap < 9; ++tap) {
            const int kh = tap / 3, kw = tap - 3 * (tap / 3);
            const short8 v = *(const short8*)
                &nhwc[((gb * H_ + ih0 + kh) * W_ + iw0 + kw) * CIN + c0 + seg * 8];
            *(short8*)&As[tap * 2048 + gm * 32 + seg * 8] = v;
        }
        // W-load: coalesced from (o, tap, c)
#pragma unroll
        for (int tap = 0; tap < 9; ++tap) {
            const short8 v = *(const short8*)
                &wgt_t[gm * KTOT + tap * CIN + c0 + seg * 8];
            *(short8*)&Ws[tap * 2048 + gm * 32 + seg * 8] = v;
        }
        __syncthreads();

        // compute: 9 K-steps; per step 5 ds_read_b128 + 4 MFMA
#pragma unroll
        for (int tap = 0; tap < 9; ++tap) {
            const short8 a = *(const short8*)
                &As[tap * 2048 + (16 * wv + ln) * 32 + hl * 8];
#pragma unroll
            for (int j = 0; j < 4; ++j) {
                const short8 b = *(const short8*)
                    &Ws[tap * 2048 + (16 * j + ln) * 32 + hl * 8];
                acc[j] = __builtin_amdgcn_mfma_f32_16x16x32_bf16(a, b, acc[j], 0, 0, 0);
            }
        }
        __syncthreads();
    }

    // epilogue: C/D layout col=ln, row=4*hl+r -> LDS -> 16-consecutive-p rows
    float* Ot = (float*)As;                 // reuse (post-barrier)
#pragma unroll
    for (int j = 0; j < 4; ++j) {
        const float bv = bias[16 * j + ln];
#pragma unroll
        for (int r = 0; r < 4; ++r)
            Ot[(16 * wv + 4 * hl + r) * LDO + 16 * j + ln] = acc[j][r] + bv;
    }
    __syncthreads();
    {
        const int o  = tid & 63;
        const int b2 = tid >> 6;
        const int rowbase = ((b0 + b2) * COUT + o) * NPIX;
#pragma unroll
        for (int pp = 0; pp < PIXT; ++pp) {
            const int p = p0 + pp;
            if (p < NPIX)
                out[rowbase + p] = Ot[(pp * 4 + b2) * LDO + o];
        }
    }
}

// ---------------- fallback (round-1 kernel) if ws too small ----------------
#define FKC   72
#define FLDA  76
__global__ __launch_bounds__(256, 4)
void sconv2davg_fallback(const float* __restrict__ in,
                         const float* __restrict__ wgt,
                         const float* __restrict__ bias,
                         const int* __restrict__ selh,
                         const int* __restrict__ selw,
                         float* __restrict__ out) {
    __shared__ float As[64 * FLDA];
    __shared__ float Ws[64 * FLDA];
    __shared__ int hb_s[4], wb_s[4];
    const int tid = threadIdx.x;
    const int p0  = blockIdx.x * 4;
    if (tid < 4) {
        int p = p0 + tid;
        if (p > NPIX - 1) p = NPIX - 1;
        int y = p / OW;
        int x = p - y * OW;
        hb_s[tid] = 2 * y + selh[p];
        wb_s[tid] = 2 * x + selw[p];
    }
    __syncthreads();
    const int tn = tid & 15, tm = tid >> 4;
    float acc[4][4];
#pragma unroll
    for (int i = 0; i < 4; ++i)
#pragma unroll
        for (int j = 0; j < 4; ++j) acc[i][j] = 0.0f;
    for (int cc = 0; cc < 8; ++cc) {
        const int c0 = cc * 8;
#pragma unroll
        for (int it = 0; it < 18; ++it) {
            int idx = tid + it * 256;
            int m = idx / FKC, rem = idx - m * FKC;
            int cl = rem / 9, r = rem - cl * 9;
            int kh = r / 3, kw = r - kh * 3;
            As[m * FLDA + rem] =
                in[((((m & 15) * CIN) + (c0 + cl)) * H_ + hb_s[m >> 4] + kh) * W_ + wb_s[m >> 4] + kw];
        }
#pragma unroll
        for (int it = 0; it < 18; ++it) {
            int idx = tid + it * 256;
            int o = idx / FKC, kk = idx - o * FKC;
            Ws[o * FLDA + kk] = wgt[o * KTOT + cc * FKC + kk];
        }
        __syncthreads();
#pragma unroll 2
        for (int k0 = 0; k0 < FKC; k0 += 4) {
            float4 a[4], w[4];
#pragma unroll
            for (int i = 0; i < 4; ++i) a[i] = *(const float4*)&As[(4 * tm + i) * FLDA + k0];
#pragma unroll
            for (int j = 0; j < 4; ++j) w[j] = *(const float4*)&Ws[(tn + 16 * j) * FLDA + k0];
#pragma unroll
            for (int i = 0; i < 4; ++i)
#pragma unroll
                for (int j = 0; j < 4; ++j) {
                    acc[i][j] += a[i].x * w[j].x; acc[i][j] += a[i].y * w[j].y;
                    acc[i][j] += a[i].z * w[j].z; acc[i][j] += a[i].w * w[j].w;
                }
        }
        __syncthreads();
    }
    const int p = p0 + (tm >> 2);
    if (p < NPIX) {
#pragma unroll
        for (int i = 0; i < 4; ++i) {
            int b = (tm & 3) * 4 + i;
#pragma unroll
            for (int j = 0; j < 4; ++j)
                out[((b * COUT) + tn + 16 * j) * NPIX + p] = acc[i][j] + bias[tn + 16 * j];
        }
    }
}

extern "C" void kernel_launch(void* const* d_in, const int* in_sizes, int n_in,
                              void* d_out, int out_size, void* d_ws, size_t ws_size,
                              hipStream_t stream) {
    const float* in   = (const float*)d_in[0];
    const float* wgt  = (const float*)d_in[1];
    const float* bias = (const float*)d_in[2];
    const int*   selh = (const int*)d_in[3];
    const int*   selw = (const int*)d_in[4];
    float* out = (float*)d_out;

    const size_t nhwc_elems = (size_t)B_ * H_ * W_ * CIN;            // 16.7M bf16
    const size_t need = (nhwc_elems + (size_t)COUT * KTOT) * 2;      // ~33.6 MB

    if (ws_size >= need) {
        short* nhwc  = (short*)d_ws;
        short* wgt_t = nhwc + nhwc_elems;
        transpose_nhwc_bf16<<<dim3(W_ / 64, H_, B_), 256, 0, stream>>>(in, nhwc);
        transpose_wgt_bf16<<<COUT, 576, 0, stream>>>(wgt, wgt_t);
        const int ptiles = (NPIX + PIXT - 1) / PIXT;                 // 249
        sconv2davg_mfma<<<dim3(ptiles, B_ / BT), 256, 0, stream>>>(
            nhwc, wgt_t, bias, selh, selw, out);
    } else {
        sconv2davg_fallback<<<(NPIX + 3) / 4, 256, 0, stream>>>(
            in, wgt, bias, selh, selw, out);
    }
}